// Round 14
// baseline (3841.704 us; speedup 1.0000x reference)
//
#include <hip/hip_runtime.h>
#include <hip/hip_cooperative_groups.h>
#include <stdint.h>

// ---------------------------------------------------------------------------
// 3-layer packed-sequence LSTM, B=64 T=2048 D=40 H=164, FC->7. fp32 in/out.
//
// v15: v13 body (best: 2297us, 64.0us steady; v12/v14 K-tail variants both
//      regressed -> step body is a verified local optimum) + persistent
//      cooperative kernel to kill the ~6us/launch prologue (37 launches:
//      launch gap + wB/wf reload + state/h round-trip + first-gx fetch).
//      kstep_coop (144 blocks, 1/CU) runs the staircase loop internally
//      with __threadfence()+grid.sync() at each iteration boundary --
//      identical dependency structure to launch boundaries. Hoisted once:
//      gemm wf/bias; rec wB/creg/hbit (regs) + h (LDS). state_c round-trip
//      eliminated; state_h written once at the end (for kfc).
//      Fallback: if hipLaunchCooperativeKernel errors, the proven v13
//      multi-launch path runs instead.
// ---------------------------------------------------------------------------

#define TT 2048
#define BB 64
#define GG 656   // 4*H (compact gate rows)
#define HH 164
#define EP 176   // padded elems per gate (16-aligned)
#define GP 704   // 4*EP padded gate rows
#define KPH 192  // K padded to 192 halves
#define KPD 96   // = KPH/2 dwords
#define CC 64    // chunk timesteps
#define NCH (TT/CC)   // 32
#define TSL 8    // timesteps per gemm slice block
#define NSL (CC/TSL)  // 8 slices
#define GEMM_BLKS (3*4*NSL)   // 96
#define REC_BLKS  48
#define NBLK_COOP (GEMM_BLKS + REC_BLKS)  // 144

typedef _Float16 half2v __attribute__((ext_vector_type(2)));
typedef _Float16 half8  __attribute__((ext_vector_type(8)));
typedef float    f32x4  __attribute__((ext_vector_type(4)));

// ---- workspace layout (bytes) ----
#define SZ_WIH   ((size_t)3*GG*KPH*2)          // f16 [3][656][192]
#define SZ_WHH   ((size_t)3*GP*KPH*2)          // f16 [3][704][192]
#define SZ_GX1   ((size_t)3*16*CC*GG*4*2)      // f16 [3][16 bg4][CC][656][4]
#define GX_SLOT_HALVES ((size_t)3*16*CC*GG*4)
#define SZ_HR    ((size_t)2*2*BB*CC*96*4)      // dw [2l][2slot][64][CC][96]
#define HR_DW    (2*2*BB*CC*96)                // ring dwords
#define SZ_SC    ((size_t)3*BB*HH*4)           // f32 c-state
#define SZ_SH    ((size_t)3*BB*96*4)           // dword h-state (f16 pairs)

#define LOG2E 1.4426950408889634f

__device__ __forceinline__ float fexp2(float x) {
#if __has_builtin(__builtin_amdgcn_exp2f)
  return __builtin_amdgcn_exp2f(x);
#else
  float r; asm("v_exp_f32 %0, %1" : "=v"(r) : "v"(x)); return r;
#endif
}
__device__ __forceinline__ float frcp(float x) {
#if __has_builtin(__builtin_amdgcn_rcpf)
  return __builtin_amdgcn_rcpf(x);
#else
  float r; asm("v_rcp_f32 %0, %1" : "=v"(r) : "v"(x)); return r;
#endif
}
__device__ __forceinline__ float sigmf(float x) {
  return frcp(1.0f + fexp2(-LOG2E * x));
}
__device__ __forceinline__ float tanhf_(float x) {
  return __builtin_fmaf(-2.0f, frcp(1.0f + fexp2(2.0f * LOG2E * x)), 1.0f);
}

// ---------------------------------------------------------------------------
// weight prep: wih compact [3][656][192] (K zero-padded), whh padded
// [3][704][192] (rows g*176+e, zero for e>=164; K zero-padded)
// ---------------------------------------------------------------------------
__global__ void kprep_w(const float* wih0, const float* whh0,
                        const float* wih1, const float* whh1,
                        const float* wih2, const float* whh2,
                        _Float16* wih16, _Float16* whh16) {
  int i = threadIdx.x + blockIdx.x * blockDim.x;
  if (i >= 3*GP*KPH) return;
  int l = i / (GP*KPH);
  int r2 = i - l*(GP*KPH);
  int prow = r2 / KPH;
  int k = r2 - prow*KPH;
  const float* wihl = (l == 0) ? wih0 : ((l == 1) ? wih1 : wih2);
  const float* whhl = (l == 0) ? whh0 : ((l == 1) ? whh1 : whh2);
  int g = prow / EP, e = prow - g*EP;
  float vh = 0.f;
  if (e < HH && k < HH) vh = whhl[(size_t)(g*HH + e)*HH + k];
  whh16[((size_t)l*GP + prow)*KPH + k] = (_Float16)vh;
  if (prow < GG) {
    float vi = 0.f;
    if (l == 0) { if (k < 40) vi = wihl[(size_t)prow*40 + k]; }
    else        { if (k < HH) vi = wihl[(size_t)prow*HH + k]; }
    wih16[((size_t)l*GG + prow)*KPH + k] = (_Float16)vi;
  }
}

// one-time ring zero (pad halves must be 0 forever; rec only writes e<164)
__global__ void kzero(uint32_t* p, int n) {
  int i = threadIdx.x + blockIdx.x * blockDim.x;
  if (i < n) p[i] = 0u;
}

// ---------------------------------------------------------------------------
// batch-major input GEMM body (fallback path): one (l, bg16, 8-t slice).
// ---------------------------------------------------------------------------
__device__ __forceinline__ void gemm_body(
    int l, int bg, int ts, int ch, const int* lengths, const float* x,
    const uint32_t* wihw, const uint32_t* hring, const float* bp,
    uint16_t* gxs, uint32_t* smem, int tid) {
  int maxlen = 1;
  #pragma unroll
  for (int bi = 0; bi < 16; ++bi) {
    int L = lengths[bg*16 + bi]; if (L < 1) L = 1; if (L > TT) L = TT;
    if (L > maxlen) maxlen = L;
  }
  const int tb = ts*TSL;
  const int t0 = ch*CC + tb;
  if (t0 >= maxlen) return;
  int tcnt = maxlen - t0; if (tcnt > TSL) tcnt = TSL;

  if (l == 0) {
    for (int idx = tid; idx < TSL*16*96; idx += 704) {
      int tloc = idx / 1536, r = idx - tloc*1536, b = r / 96, dw = r - b*96;
      uint32_t v = 0;
      if (dw < 20) {
        const float* xs = x + ((size_t)(bg*16 + b)*TT + (t0 + tloc))*40 + dw*2;
        half2v pp; pp[0] = (_Float16)xs[0]; pp[1] = (_Float16)xs[1];
        v = __builtin_bit_cast(uint32_t, pp);
      }
      smem[(tloc*16 + b)*100 + dw] = v;
    }
  } else {
    const uint32_t* hbs = hring + ((size_t)((l-1)*2 + (ch & 1))*BB)*CC*96;
    for (int idx = tid; idx < TSL*16*96; idx += 704) {
      int tloc = idx / 1536, r = idx - tloc*1536, b = r / 96, dw = r - b*96;
      smem[(tloc*16 + b)*100 + dw] =
          hbs[((size_t)(bg*16 + b)*CC + tb + tloc)*96 + dw];
    }
  }
  __syncthreads();

  const int lane = tid & 63, wv = tid >> 6;
  const int quad = lane >> 4, n15 = lane & 15;
  uint16_t* gxo = gxs + (((size_t)(l*16 + bg*4 + quad)*CC + tb)*GG)*4;

  half8 wf[4][6];
  float bv[4] = {0.f, 0.f, 0.f, 0.f};
  #pragma unroll
  for (int ni = 0; ni < 4; ++ni) {
    int nt = wv + ni*11;
    if (nt < 41) {
      int wrow = nt*16 + n15;
      const half8* bsrc = (const half8*)(wihw + ((size_t)l*GG + wrow)*KPD);
      #pragma unroll
      for (int kk = 0; kk < 6; ++kk) wf[ni][kk] = bsrc[kk*4 + quad];
      bv[ni] = bp[wrow];
    }
  }

  for (int tloc = 0; tloc < tcnt; ++tloc) {
    const half8* asrc = (const half8*)(smem + tloc*1600);
    half8 af[6];
    #pragma unroll
    for (int kk = 0; kk < 6; ++kk) af[kk] = asrc[n15*25 + kk*4 + quad];
    #pragma unroll
    for (int ni = 0; ni < 4; ++ni) {
      int nt = wv + ni*11;
      if (nt < 41) {
        int wrow = nt*16 + n15;
        f32x4 a0 = {0.f,0.f,0.f,0.f};
        #pragma unroll
        for (int kk = 0; kk < 6; ++kk)
          a0 = __builtin_amdgcn_mfma_f32_16x16x32_f16(af[kk], wf[ni][kk], a0, 0, 0, 0);
        half2v p0; p0[0] = (_Float16)(a0[0] + bv[ni]); p0[1] = (_Float16)(a0[1] + bv[ni]);
        half2v p1; p1[0] = (_Float16)(a0[2] + bv[ni]); p1[1] = (_Float16)(a0[3] + bv[ni]);
        uint2 pk;
        pk.x = __builtin_bit_cast(uint32_t, p0);
        pk.y = __builtin_bit_cast(uint32_t, p1);
        *(uint2*)(gxo + ((size_t)tloc*GG + wrow)*4) = pk;
      }
    }
  }
}

// ---------------------------------------------------------------------------
// MFMA recurrence body (fallback path): one (l, bg4, chunk).
// ---------------------------------------------------------------------------
__device__ __forceinline__ void rec_body(
    int l, int bg, int ch, const int* lengths,
    const uint32_t* whhw, const uint16_t* gxs, uint32_t* hring,
    float* state_c, uint32_t* state_h, uint32_t* smem, int tid) {

  const int gb0 = bg*4;
  int maxlen = 1;
  #pragma unroll
  for (int bi = 0; bi < 4; ++bi) {
    int L = lengths[gb0 + bi]; if (L < 1) L = 1; if (L > TT) L = TT;
    if (L > maxlen) maxlen = L;
  }
  const int t0 = ch*CC;
  if (t0 >= maxlen) return;
  int t1 = t0 + CC; if (t1 > maxlen) t1 = maxlen;
  const int nst = t1 - t0;

  const int wv = tid >> 6, ln = tid & 63;
  const int quad = ln >> 4, n15 = ln & 15;
  const int e = wv*16 + n15;
  const int evalid = (e < HH);
  const int gb = gb0 + quad;

  int lenq = lengths[gb]; if (lenq < 1) lenq = 1; if (lenq > TT) lenq = TT;

  half8 wB[24];
  {
    const half8* wb8 = (const half8*)(whhw + (size_t)l*GP*KPD);
    #pragma unroll
    for (int g = 0; g < 4; ++g) {
      int row = g*EP + e;
      #pragma unroll
      for (int kk = 0; kk < 6; ++kk)
        wB[g*6 + kk] = wb8[(size_t)row*24 + kk*4 + quad];
    }
  }

  float creg = 0.f;
  if (ch > 0 && evalid)
    creg = state_c[((size_t)l*BB + gb)*HH + e];

  uint32_t* hb0 = smem;
  uint32_t* hb1 = smem + 1600;
  for (int i2 = tid; i2 < 1600; i2 += 704) {
    int bb = i2 / 100, dd = i2 - bb*100;
    uint32_t v = 0;
    if (dd < 96 && ch > 0) v = state_h[((size_t)l*BB + gb0 + (bb >> 2))*96 + dd];
    hb0[i2] = v; hb1[i2] = v;
  }
  __syncthreads();

  uint16_t hbit = ((const uint16_t*)hb0)[(quad*4)*200 + e];

  const uint16_t* gpt = gxs + (((size_t)(l*16 + bg)*CC)*GG)*4
                            + (size_t)e*4 + quad;
  uint16_t gxv[4];
  #pragma unroll
  for (int g = 0; g < 4; ++g) gxv[g] = gpt[g*(HH*4)];
  gpt += GG*4;

  const int dorb = (l < 2);
  uint16_t* rp;
  {
    uint16_t* hrb16 = (uint16_t*)(hring + ((size_t)(l*2 + (ch & 1))*BB)*CC*96);
    rp = hrb16 + ((size_t)gb*CC)*192 + e;
  }

  const int lo = n15*100 + quad*4;
  const int ho_off = (quad*4)*200 + e;

  int p = 0;
  for (int it = 0; it < nst; ++it) {
    const int t = t0 + it;
    uint32_t* hin  = p ? hb1 : hb0;
    uint32_t* hout = p ? hb0 : hb1;

    float gxf0 = (float)__builtin_bit_cast(_Float16, gxv[0]);
    float gxf1 = (float)__builtin_bit_cast(_Float16, gxv[1]);
    float gxf2 = (float)__builtin_bit_cast(_Float16, gxv[2]);
    float gxf3 = (float)__builtin_bit_cast(_Float16, gxv[3]);
    #pragma unroll
    for (int g = 0; g < 4; ++g) gxv[g] = gpt[g*(HH*4)];
    gpt += GG*4;

    f32x4 acc0, acc1, acc2, acc3;
    {
      const f32x4 z = {0.f, 0.f, 0.f, 0.f};
      half8 af = *(const half8*)&hin[lo];
      acc0 = __builtin_amdgcn_mfma_f32_16x16x32_f16(af, wB[0],  z, 0, 0, 0);
      acc1 = __builtin_amdgcn_mfma_f32_16x16x32_f16(af, wB[6],  z, 0, 0, 0);
      acc2 = __builtin_amdgcn_mfma_f32_16x16x32_f16(af, wB[12], z, 0, 0, 0);
      acc3 = __builtin_amdgcn_mfma_f32_16x16x32_f16(af, wB[18], z, 0, 0, 0);
    }
    #pragma unroll
    for (int kk = 1; kk < 6; ++kk) {
      half8 af = *(const half8*)&hin[lo + kk*16];
      acc0 = __builtin_amdgcn_mfma_f32_16x16x32_f16(af, wB[kk],      acc0, 0, 0, 0);
      acc1 = __builtin_amdgcn_mfma_f32_16x16x32_f16(af, wB[6 + kk],  acc1, 0, 0, 0);
      acc2 = __builtin_amdgcn_mfma_f32_16x16x32_f16(af, wB[12 + kk], acc2, 0, 0, 0);
      acc3 = __builtin_amdgcn_mfma_f32_16x16x32_f16(af, wB[18 + kk], acc3, 0, 0, 0);
    }
    {
      float gi = acc0[0] + gxf0;
      float gf = acc1[0] + gxf1;
      float gg2 = acc2[0] + gxf2;
      float go = acc3[0] + gxf3;
      float cn = sigmf(gf)*creg + sigmf(gi)*tanhf_(gg2);
      float hv = sigmf(go)*tanhf_(cn);
      if (t < lenq) {
        creg = cn;
        _Float16 h16 = (_Float16)hv;
        hbit = __builtin_bit_cast(uint16_t, h16);
      }
      if (evalid) {
        ((uint16_t*)hout)[ho_off] = hbit;
        if (dorb) *rp = hbit;
      }
      rp += 192;
    }
    asm volatile("s_waitcnt lgkmcnt(0)" ::: "memory");
    __builtin_amdgcn_s_barrier();
    p ^= 1;
  }

  uint32_t* hfin = p ? hb1 : hb0;
  uint32_t* shb = state_h + ((size_t)l*BB + gb0)*96;
  for (int i2 = tid; i2 < 4*96; i2 += 704) {
    int bb = i2 / 96, dd = i2 - bb*96;
    shb[(size_t)bb*96 + dd] = hfin[(bb*4)*100 + dd];
  }
  if (evalid)
    state_c[((size_t)l*BB + gb)*HH + e] = creg;
}

// ---------------------------------------------------------------------------
// PERSISTENT cooperative kernel: the whole staircase in one launch.
// blocks 0..95 = gemm role (l,bg,ts fixed); 96..143 = rec role (l,bg fixed).
// grid.sync() replaces launch boundaries (same dependency structure).
// ---------------------------------------------------------------------------
__global__ __launch_bounds__(704, 1) void kstep_coop(
    const int* lengths, const float* x,
    const uint32_t* wihw, const uint32_t* whhw,
    const float* b0, const float* b1, const float* b2,
    uint16_t* gx, uint32_t* hring, uint32_t* state_h) {
  cooperative_groups::grid_group grid = cooperative_groups::this_grid();
  __shared__ __align__(16) uint32_t smem[TSL*1600];     // 51.2 KB
  const int blk = blockIdx.x, tid = threadIdx.x;

  if (blk < GEMM_BLKS) {
    // ================= persistent gemm role =================
    const int l = blk / (4*NSL);
    const int r = blk - l*(4*NSL);
    const int bg = r / NSL, ts = r - bg*NSL;
    const int tb = ts*TSL;
    int maxlen = 1;
    #pragma unroll
    for (int bi = 0; bi < 16; ++bi) {
      int L = lengths[bg*16 + bi]; if (L < 1) L = 1; if (L > TT) L = TT;
      if (L > maxlen) maxlen = L;
    }
    const int lane = tid & 63, wv = tid >> 6;
    const int quad = lane >> 4, n15 = lane & 15;
    const float* bp = (l == 0) ? b0 : ((l == 1) ? b1 : b2);

    // hoisted ONCE for all chunks: W_ih fragments + bias
    half8 wf[4][6];
    float bv[4] = {0.f, 0.f, 0.f, 0.f};
    #pragma unroll
    for (int ni = 0; ni < 4; ++ni) {
      int nt = wv + ni*11;
      if (nt < 41) {
        int wrow = nt*16 + n15;
        const half8* bsrc = (const half8*)(wihw + ((size_t)l*GG + wrow)*KPD);
        #pragma unroll
        for (int kk = 0; kk < 6; ++kk) wf[ni][kk] = bsrc[kk*4 + quad];
        bv[ni] = bp[wrow];
      }
    }

    for (int j = 0; j <= NCH + 4; ++j) {
      const int ch = j - 2*l;
      if (ch >= 0 && ch < NCH) {
        const int t0 = ch*CC + tb;
        if (t0 < maxlen) {
          int tcnt = maxlen - t0; if (tcnt > TSL) tcnt = TSL;
          uint16_t* gxs = gx + (size_t)(ch & 1)*GX_SLOT_HALVES;
          // stage A
          if (l == 0) {
            for (int idx = tid; idx < TSL*16*96; idx += 704) {
              int tloc = idx / 1536, rr = idx - tloc*1536, b = rr / 96, dw = rr - b*96;
              uint32_t v = 0;
              if (dw < 20) {
                const float* xs = x + ((size_t)(bg*16 + b)*TT + (t0 + tloc))*40 + dw*2;
                half2v pp; pp[0] = (_Float16)xs[0]; pp[1] = (_Float16)xs[1];
                v = __builtin_bit_cast(uint32_t, pp);
              }
              smem[(tloc*16 + b)*100 + dw] = v;
            }
          } else {
            const uint32_t* hbs = hring + ((size_t)((l-1)*2 + (ch & 1))*BB)*CC*96;
            for (int idx = tid; idx < TSL*16*96; idx += 704) {
              int tloc = idx / 1536, rr = idx - tloc*1536, b = rr / 96, dw = rr - b*96;
              smem[(tloc*16 + b)*100 + dw] =
                  hbs[((size_t)(bg*16 + b)*CC + tb + tloc)*96 + dw];
            }
          }
          __syncthreads();
          uint16_t* gxo = gxs + (((size_t)(l*16 + bg*4 + quad)*CC + tb)*GG)*4;
          for (int tloc = 0; tloc < tcnt; ++tloc) {
            const half8* asrc = (const half8*)(smem + tloc*1600);
            half8 af[6];
            #pragma unroll
            for (int kk = 0; kk < 6; ++kk) af[kk] = asrc[n15*25 + kk*4 + quad];
            #pragma unroll
            for (int ni = 0; ni < 4; ++ni) {
              int nt = wv + ni*11;
              if (nt < 41) {
                int wrow = nt*16 + n15;
                f32x4 a0 = {0.f,0.f,0.f,0.f};
                #pragma unroll
                for (int kk = 0; kk < 6; ++kk)
                  a0 = __builtin_amdgcn_mfma_f32_16x16x32_f16(af[kk], wf[ni][kk], a0, 0, 0, 0);
                half2v p0; p0[0] = (_Float16)(a0[0] + bv[ni]); p0[1] = (_Float16)(a0[1] + bv[ni]);
                half2v p1; p1[0] = (_Float16)(a0[2] + bv[ni]); p1[1] = (_Float16)(a0[3] + bv[ni]);
                uint2 pk;
                pk.x = __builtin_bit_cast(uint32_t, p0);
                pk.y = __builtin_bit_cast(uint32_t, p1);
                *(uint2*)(gxo + ((size_t)tloc*GG + wrow)*4) = pk;
              }
            }
          }
        }
      }
      __threadfence();
      grid.sync();
    }
  } else {
    // ================= persistent rec role =================
    const int idx0 = blk - GEMM_BLKS;           // 0..47
    const int l = idx0 >> 4, bg = idx0 & 15;
    const int gb0 = bg*4;
    int maxlen = 1;
    #pragma unroll
    for (int bi = 0; bi < 4; ++bi) {
      int L = lengths[gb0 + bi]; if (L < 1) L = 1; if (L > TT) L = TT;
      if (L > maxlen) maxlen = L;
    }
    const int wv = tid >> 6, ln = tid & 63;
    const int quad = ln >> 4, n15 = ln & 15;
    const int e = wv*16 + n15;
    const int evalid = (e < HH);
    const int gb = gb0 + quad;
    int lenq = lengths[gb]; if (lenq < 1) lenq = 1; if (lenq > TT) lenq = TT;

    // hoisted ONCE: W_hh fragments (AGPR-resident across all chunks)
    half8 wB[24];
    {
      const half8* wb8 = (const half8*)(whhw + (size_t)l*GP*KPD);
      #pragma unroll
      for (int g = 0; g < 4; ++g) {
        int row = g*EP + e;
        #pragma unroll
        for (int kk = 0; kk < 6; ++kk)
          wB[g*6 + kk] = wb8[(size_t)row*24 + kk*4 + quad];
      }
    }
    // persistent state: c, h-bits in regs; h in LDS (zeros at t=0)
    float creg = 0.f;
    uint16_t hbit = 0;
    uint32_t* hb0 = smem;
    uint32_t* hb1 = smem + 1600;
    for (int i2 = tid; i2 < 1600; i2 += 704) { hb0[i2] = 0u; hb1[i2] = 0u; }
    __syncthreads();

    const int lo = n15*100 + quad*4;
    const int ho_off = (quad*4)*200 + e;
    const int dorb = (l < 2);
    int p = 0;

    for (int j = 0; j <= NCH + 4; ++j) {
      const int ch = j - 2*l - 1;
      if (ch >= 0 && ch < NCH && ch*CC < maxlen) {
        const int t0 = ch*CC;
        int t1 = t0 + CC; if (t1 > maxlen) t1 = maxlen;
        const uint16_t* gxs = gx + (size_t)(ch & 1)*GX_SLOT_HALVES;
        const uint16_t* gpt = gxs + (((size_t)(l*16 + bg)*CC)*GG)*4
                                  + (size_t)e*4 + quad;
        uint16_t gxv[4];
        #pragma unroll
        for (int g = 0; g < 4; ++g) gxv[g] = gpt[g*(HH*4)];
        gpt += GG*4;
        uint16_t* rp = (uint16_t*)(hring + ((size_t)(l*2 + (ch & 1))*BB)*CC*96)
                       + ((size_t)gb*CC)*192 + e;

        for (int t = t0; t < t1; ++t) {
          uint32_t* hin  = p ? hb1 : hb0;
          uint32_t* hout = p ? hb0 : hb1;

          float gxf0 = (float)__builtin_bit_cast(_Float16, gxv[0]);
          float gxf1 = (float)__builtin_bit_cast(_Float16, gxv[1]);
          float gxf2 = (float)__builtin_bit_cast(_Float16, gxv[2]);
          float gxf3 = (float)__builtin_bit_cast(_Float16, gxv[3]);
          #pragma unroll
          for (int g = 0; g < 4; ++g) gxv[g] = gpt[g*(HH*4)];
          gpt += GG*4;

          f32x4 acc0, acc1, acc2, acc3;
          {
            const f32x4 z = {0.f, 0.f, 0.f, 0.f};
            half8 af = *(const half8*)&hin[lo];
            acc0 = __builtin_amdgcn_mfma_f32_16x16x32_f16(af, wB[0],  z, 0, 0, 0);
            acc1 = __builtin_amdgcn_mfma_f32_16x16x32_f16(af, wB[6],  z, 0, 0, 0);
            acc2 = __builtin_amdgcn_mfma_f32_16x16x32_f16(af, wB[12], z, 0, 0, 0);
            acc3 = __builtin_amdgcn_mfma_f32_16x16x32_f16(af, wB[18], z, 0, 0, 0);
          }
          #pragma unroll
          for (int kk = 1; kk < 6; ++kk) {
            half8 af = *(const half8*)&hin[lo + kk*16];
            acc0 = __builtin_amdgcn_mfma_f32_16x16x32_f16(af, wB[kk],      acc0, 0, 0, 0);
            acc1 = __builtin_amdgcn_mfma_f32_16x16x32_f16(af, wB[6 + kk],  acc1, 0, 0, 0);
            acc2 = __builtin_amdgcn_mfma_f32_16x16x32_f16(af, wB[12 + kk], acc2, 0, 0, 0);
            acc3 = __builtin_amdgcn_mfma_f32_16x16x32_f16(af, wB[18 + kk], acc3, 0, 0, 0);
          }
          {
            float gi = acc0[0] + gxf0;
            float gf = acc1[0] + gxf1;
            float gg2 = acc2[0] + gxf2;
            float go = acc3[0] + gxf3;
            float cn = sigmf(gf)*creg + sigmf(gi)*tanhf_(gg2);
            float hv = sigmf(go)*tanhf_(cn);
            if (t < lenq) {
              creg = cn;
              _Float16 h16 = (_Float16)hv;
              hbit = __builtin_bit_cast(uint16_t, h16);
            }
            if (evalid) {
              ((uint16_t*)hout)[ho_off] = hbit;
              if (dorb) *rp = hbit;
            }
            rp += 192;
          }
          asm volatile("s_waitcnt lgkmcnt(0)" ::: "memory");
          __builtin_amdgcn_s_barrier();
          p ^= 1;
        }
      }
      __threadfence();
      grid.sync();
    }

    // final: persist h for kfc
    uint32_t* hfin = p ? hb1 : hb0;
    uint32_t* shb = state_h + ((size_t)l*BB + gb0)*96;
    for (int i2 = tid; i2 < 4*96; i2 += 704) {
      int bb = i2 / 96, dd = i2 - bb*96;
      shb[(size_t)bb*96 + dd] = hfin[(bb*4)*100 + dd];
    }
  }
}

// ---------------------------------------------------------------------------
// v13 fused step (fallback if cooperative launch unavailable)
// ---------------------------------------------------------------------------
__global__ __launch_bounds__(704, 1) void kstep_f(
    int j, const int* lengths, const float* x,
    const uint32_t* wihw, const uint32_t* whhw,
    const float* b0, const float* b1, const float* b2,
    uint16_t* gx, uint32_t* hring, float* state_c, uint32_t* state_h) {
  __shared__ __align__(16) uint32_t smem[TSL*1600];
  const int blk = blockIdx.x, tid = threadIdx.x;
  if (blk < GEMM_BLKS) {
    const int l = blk / (4*NSL);
    const int r = blk - l*(4*NSL);
    const int bg = r / NSL, ts = r - bg*NSL;
    const int ch = j - 2*l;
    if (ch < 0 || ch >= NCH) return;
    const float* bp = (l == 0) ? b0 : ((l == 1) ? b1 : b2);
    uint16_t* gxs = gx + (size_t)(ch & 1)*GX_SLOT_HALVES;
    gemm_body(l, bg, ts, ch, lengths, x, wihw, hring, bp, gxs, smem, tid);
  } else {
    const int idx = blk - GEMM_BLKS;
    if (idx >= REC_BLKS) return;
    const int l = idx >> 4, bg = idx & 15;
    const int ch = j - 2*l - 1;
    if (ch < 0 || ch >= NCH) return;
    const uint16_t* gxs = gx + (size_t)(ch & 1)*GX_SLOT_HALVES;
    rec_body(l, bg, ch, lengths, whhw, gxs, hring,
             state_c, state_h, smem, tid);
  }
}

// ---- sequential fallback (1 gx slot) ----
__global__ __launch_bounds__(704, 1) void kgemm_s(
    int step, const int* lengths, const float* x,
    const uint32_t* wihw, const float* b0, const float* b1, const float* b2,
    uint16_t* gx, const uint32_t* hring) {
  __shared__ __align__(16) uint32_t smem[TSL*1600];
  const int blk = blockIdx.x;
  const int l = blk / (4*NSL);
  const int r = blk - l*(4*NSL);
  const int bg = r / NSL, ts = r - bg*NSL;
  const int ch = step - l;
  if (ch < 0 || ch >= NCH) return;
  const float* bp = (l == 0) ? b0 : ((l == 1) ? b1 : b2);
  gemm_body(l, bg, ts, ch, lengths, x, wihw, hring, bp, gx, smem, threadIdx.x);
}

__global__ __launch_bounds__(704, 1) void krec_s(
    int step, const int* lengths,
    const uint32_t* whhw, const uint16_t* gx, uint32_t* hring,
    float* state_c, uint32_t* state_h) {
  __shared__ __align__(16) uint32_t smem[TSL*1600];
  const int idx = blockIdx.x;
  const int l = idx >> 4, bg = idx & 15;
  const int ch = step - l;
  if (ch < 0 || ch >= NCH) return;
  rec_body(l, bg, ch, lengths, whhw, gx, hring,
           state_c, state_h, smem, threadIdx.x);
}

// ---------------------------------------------------------------------------
// FC epilogue on layer-2 final hidden state
// ---------------------------------------------------------------------------
__global__ void kfc(const float* fcw, const float* fcb,
                    const uint32_t* state_h, float* out) {
  int b = blockIdx.x, o = threadIdx.x;
  if (o >= 7) return;
  const uint16_t* h16 = (const uint16_t*)(state_h + (size_t)(2*BB + b)*96);
  float s = fcb[o];
  for (int m = 0; m < HH; ++m) {
    _Float16 hv = __builtin_bit_cast(_Float16, h16[m]);
    s += fcw[o*HH + m] * (float)hv;
  }
  out[b*7 + o] = s;
}

// ---------------------------------------------------------------------------
extern "C" void kernel_launch(void* const* d_in, const int* in_sizes, int n_in,
                              void* d_out, int out_size, void* d_ws, size_t ws_size,
                              hipStream_t stream) {
  const float* x      = (const float*)d_in[0];
  const int*  lengths = (const int*)  d_in[1];
  const float* wih0   = (const float*)d_in[2];
  const float* whh0   = (const float*)d_in[3];
  const float* b0     = (const float*)d_in[4];
  const float* wih1   = (const float*)d_in[5];
  const float* whh1   = (const float*)d_in[6];
  const float* b1     = (const float*)d_in[7];
  const float* wih2   = (const float*)d_in[8];
  const float* whh2   = (const float*)d_in[9];
  const float* b2     = (const float*)d_in[10];
  const float* fcw    = (const float*)d_in[11];
  const float* fcb    = (const float*)d_in[12];

  const size_t off_wih = 0;
  const size_t off_whh = SZ_WIH;
  const size_t off_gx  = SZ_WIH + SZ_WHH;
  const size_t tail    = SZ_HR + SZ_SC + SZ_SH;
  const size_t need_fused = off_gx + 2*SZ_GX1 + tail;
  const size_t need_seq   = off_gx + 1*SZ_GX1 + tail;
  const int fused = (ws_size >= need_fused);
  if (!fused && ws_size < need_seq) return;             // loud, clean failure
  const size_t gx_bytes = fused ? 2*SZ_GX1 : SZ_GX1;
  const size_t off_hr = off_gx + gx_bytes;
  const size_t off_sc = off_hr + SZ_HR;
  const size_t off_sh = off_sc + SZ_SC;

  char* ws = (char*)d_ws;
  _Float16* wih16 = (_Float16*)(ws + off_wih);
  _Float16* whh16 = (_Float16*)(ws + off_whh);
  uint16_t* gxw   = (uint16_t*)(ws + off_gx);
  uint32_t* hrw   = (uint32_t*)(ws + off_hr);
  float*    scw   = (float*)   (ws + off_sc);
  uint32_t* shw   = (uint32_t*)(ws + off_sh);

  hipLaunchKernelGGL(kprep_w, dim3((3*GP*KPH + 255)/256), dim3(256), 0, stream,
                     wih0, whh0, wih1, whh1, wih2, whh2, wih16, whh16);
  hipLaunchKernelGGL(kzero, dim3((HR_DW + 255)/256), dim3(256), 0, stream,
                     hrw, HR_DW);

  int done = 0;
  if (fused) {
    // persistent cooperative path (kills the ~6us/launch prologue)
    const uint32_t* wihc = (const uint32_t*)wih16;
    const uint32_t* whhc = (const uint32_t*)whh16;
    void* kargs[] = {
      (void*)&lengths, (void*)&x, (void*)&wihc, (void*)&whhc,
      (void*)&b0, (void*)&b1, (void*)&b2,
      (void*)&gxw, (void*)&hrw, (void*)&shw
    };
    hipError_t err = hipLaunchCooperativeKernel(
        (const void*)kstep_coop, dim3(NBLK_COOP), dim3(704), kargs, 0, stream);
    if (err == hipSuccess) done = 1;
  }
  if (!done && fused) {
    for (int jj = 0; jj <= NCH + 4; ++jj) {
      hipLaunchKernelGGL(kstep_f, dim3(NBLK_COOP), dim3(704), 0,
                         stream, jj, lengths, x, (const uint32_t*)wih16,
                         (const uint32_t*)whh16, b0, b1, b2,
                         gxw, hrw, scw, shw);
    }
    done = 1;
  }
  if (!done) {
    for (int i = 0; i < NCH + 2; ++i) {
      hipLaunchKernelGGL(kgemm_s, dim3(GEMM_BLKS), dim3(704), 0, stream,
                         i, lengths, x, (const uint32_t*)wih16,
                         b0, b1, b2, gxw, (const uint32_t*)hrw);
      hipLaunchKernelGGL(krec_s, dim3(REC_BLKS), dim3(704), 0, stream,
                         i, lengths, (const uint32_t*)whh16,
                         (const uint16_t*)gxw, hrw, scw, shw);
    }
  }

  hipLaunchKernelGGL(kfc, dim3(64), dim3(64), 0, stream,
                     fcw, fcb, shw, (float*)d_out);
}

// Round 15
// 2294.565 us; speedup vs baseline: 1.6743x; 1.6743x over previous
//
#include <hip/hip_runtime.h>
#include <stdint.h>

// ---------------------------------------------------------------------------
// 3-layer packed-sequence LSTM, B=64 T=2048 D=40 H=164, FC->7. fp32 in/out.
//
// v16 = v13 exactly (best verified: 2297us total, 64.0us steady), reverting
// the v15 cooperative-kernel excursion (grid.sync on 144 blocks/8 XCDs costs
// ~40us vs the ~6us launch boundary it replaced -> 3841us total).
//
// Final calibration (15 rounds):
//  * step body 0.914us (2190cy): per-SIMD MFMA issue floor ~1400cy (264
//    MFMA/block-step frozen by the h-dependency), rest ds_read/VALU/trans/
//    barrier overlap. Survived 3 attacks (v11 pairing +-0, v12 tail -8%,
//    v14 early-tail -14%) -> verified local optimum.
//  * geometry: wall = (NCH+5) x (CC x step + ~6us prologue); CC=64 is the
//    minimum (CC=32 => ~2430, CC=128 => ~2583 modeled).
//  * launch boundary IS the cheapest grid-wide barrier on MI355X.
//  Remaining gap to counter-roofline is the serial 2368-step h->h chain:
//  structural, not bandwidth/compute.
// ---------------------------------------------------------------------------

#define TT 2048
#define BB 64
#define GG 656   // 4*H (compact gate rows)
#define HH 164
#define EP 176   // padded elems per gate (16-aligned)
#define GP 704   // 4*EP padded gate rows
#define KPH 192  // K padded to 192 halves
#define KPD 96   // = KPH/2 dwords
#define CC 64    // chunk timesteps
#define NCH (TT/CC)   // 32
#define TSL 8    // timesteps per gemm slice block
#define NSL (CC/TSL)  // 8 slices
#define GEMM_BLKS (3*4*NSL)   // 96
#define REC_BLKS  48

typedef _Float16 half2v __attribute__((ext_vector_type(2)));
typedef _Float16 half8  __attribute__((ext_vector_type(8)));
typedef float    f32x4  __attribute__((ext_vector_type(4)));

// ---- workspace layout (bytes) ----
#define SZ_WIH   ((size_t)3*GG*KPH*2)          // f16 [3][656][192]
#define SZ_WHH   ((size_t)3*GP*KPH*2)          // f16 [3][704][192]
#define SZ_GX1   ((size_t)3*16*CC*GG*4*2)      // f16 [3][16 bg4][CC][656][4]
#define GX_SLOT_HALVES ((size_t)3*16*CC*GG*4)
#define SZ_HR    ((size_t)2*2*BB*CC*96*4)      // dw [2l][2slot][64][CC][96]
#define HR_DW    (2*2*BB*CC*96)                // ring dwords
#define SZ_SC    ((size_t)3*BB*HH*4)           // f32 c-state
#define SZ_SH    ((size_t)3*BB*96*4)           // dword h-state (f16 pairs)

#define LOG2E 1.4426950408889634f

__device__ __forceinline__ float fexp2(float x) {
#if __has_builtin(__builtin_amdgcn_exp2f)
  return __builtin_amdgcn_exp2f(x);
#else
  float r; asm("v_exp_f32 %0, %1" : "=v"(r) : "v"(x)); return r;
#endif
}
__device__ __forceinline__ float frcp(float x) {
#if __has_builtin(__builtin_amdgcn_rcpf)
  return __builtin_amdgcn_rcpf(x);
#else
  float r; asm("v_rcp_f32 %0, %1" : "=v"(r) : "v"(x)); return r;
#endif
}
__device__ __forceinline__ float sigmf(float x) {
  return frcp(1.0f + fexp2(-LOG2E * x));
}
__device__ __forceinline__ float tanhf_(float x) {
  return __builtin_fmaf(-2.0f, frcp(1.0f + fexp2(2.0f * LOG2E * x)), 1.0f);
}

// ---------------------------------------------------------------------------
// weight prep: wih compact [3][656][192] (K zero-padded), whh padded
// [3][704][192] (rows g*176+e, zero for e>=164; K zero-padded)
// ---------------------------------------------------------------------------
__global__ void kprep_w(const float* wih0, const float* whh0,
                        const float* wih1, const float* whh1,
                        const float* wih2, const float* whh2,
                        _Float16* wih16, _Float16* whh16) {
  int i = threadIdx.x + blockIdx.x * blockDim.x;
  if (i >= 3*GP*KPH) return;
  int l = i / (GP*KPH);
  int r2 = i - l*(GP*KPH);
  int prow = r2 / KPH;
  int k = r2 - prow*KPH;
  const float* wihl = (l == 0) ? wih0 : ((l == 1) ? wih1 : wih2);
  const float* whhl = (l == 0) ? whh0 : ((l == 1) ? whh1 : whh2);
  int g = prow / EP, e = prow - g*EP;
  float vh = 0.f;
  if (e < HH && k < HH) vh = whhl[(size_t)(g*HH + e)*HH + k];
  whh16[((size_t)l*GP + prow)*KPH + k] = (_Float16)vh;
  if (prow < GG) {
    float vi = 0.f;
    if (l == 0) { if (k < 40) vi = wihl[(size_t)prow*40 + k]; }
    else        { if (k < HH) vi = wihl[(size_t)prow*HH + k]; }
    wih16[((size_t)l*GG + prow)*KPH + k] = (_Float16)vi;
  }
}

// one-time ring zero (pad halves must be 0 forever; rec only writes e<164)
__global__ void kzero(uint32_t* p, int n) {
  int i = threadIdx.x + blockIdx.x * blockDim.x;
  if (i < n) p[i] = 0u;
}

// ---------------------------------------------------------------------------
// batch-major input GEMM: one (l, 16-batch group, 8-t slice). 704 thr.
// ---------------------------------------------------------------------------
__device__ __forceinline__ void gemm_body(
    int l, int bg, int ts, int ch, const int* lengths, const float* x,
    const uint32_t* wihw, const uint32_t* hring, const float* bp,
    uint16_t* gxs, uint32_t* smem, int tid) {
  int maxlen = 1;
  #pragma unroll
  for (int bi = 0; bi < 16; ++bi) {
    int L = lengths[bg*16 + bi]; if (L < 1) L = 1; if (L > TT) L = TT;
    if (L > maxlen) maxlen = L;
  }
  const int tb = ts*TSL;                        // local t base within chunk
  const int t0 = ch*CC + tb;                    // absolute t base
  if (t0 >= maxlen) return;
  int tcnt = maxlen - t0; if (tcnt > TSL) tcnt = TSL;

  // ---- stage A: [TSL][16 batches][100 dw], full 96 dw (zeros pad K) ----
  if (l == 0) {
    for (int idx = tid; idx < TSL*16*96; idx += 704) {
      int tloc = idx / 1536, r = idx - tloc*1536, b = r / 96, dw = r - b*96;
      uint32_t v = 0;
      if (dw < 20) {
        const float* xs = x + ((size_t)(bg*16 + b)*TT + (t0 + tloc))*40 + dw*2;
        half2v pp; pp[0] = (_Float16)xs[0]; pp[1] = (_Float16)xs[1];
        v = __builtin_bit_cast(uint32_t, pp);
      }
      smem[(tloc*16 + b)*100 + dw] = v;
    }
  } else {
    const uint32_t* hbs = hring + ((size_t)((l-1)*2 + (ch & 1))*BB)*CC*96;
    for (int idx = tid; idx < TSL*16*96; idx += 704) {
      int tloc = idx / 1536, r = idx - tloc*1536, b = r / 96, dw = r - b*96;
      smem[(tloc*16 + b)*100 + dw] =
          hbs[((size_t)(bg*16 + b)*CC + tb + tloc)*96 + dw];
    }
  }
  __syncthreads();

  const int lane = tid & 63, wv = tid >> 6;
  const int quad = lane >> 4, n15 = lane & 15;
  // per-lane gx slab: (l*16 + bg*4 + quad), rows tb..
  uint16_t* gxo = gxs + (((size_t)(l*16 + bg*4 + quad)*CC + tb)*GG)*4;

  // ---- hoisted W_ih fragments + bias (static indices; regs) ----
  half8 wf[4][6];
  float bv[4] = {0.f, 0.f, 0.f, 0.f};
  #pragma unroll
  for (int ni = 0; ni < 4; ++ni) {
    int nt = wv + ni*11;
    if (nt < 41) {
      int wrow = nt*16 + n15;
      const half8* bsrc = (const half8*)(wihw + ((size_t)l*GG + wrow)*KPD);
      #pragma unroll
      for (int kk = 0; kk < 6; ++kk) wf[ni][kk] = bsrc[kk*4 + quad];
      bv[ni] = bp[wrow];
    }
  }

  for (int tloc = 0; tloc < tcnt; ++tloc) {
    const half8* asrc = (const half8*)(smem + tloc*1600); // batch stride 25 h8
    half8 af[6];
    #pragma unroll
    for (int kk = 0; kk < 6; ++kk) af[kk] = asrc[n15*25 + kk*4 + quad];
    #pragma unroll
    for (int ni = 0; ni < 4; ++ni) {
      int nt = wv + ni*11;
      if (nt < 41) {
        int wrow = nt*16 + n15;
        f32x4 a0 = {0.f,0.f,0.f,0.f};
        #pragma unroll
        for (int kk = 0; kk < 6; ++kk)
          a0 = __builtin_amdgcn_mfma_f32_16x16x32_f16(af[kk], wf[ni][kk], a0, 0, 0, 0);
        half2v p0; p0[0] = (_Float16)(a0[0] + bv[ni]); p0[1] = (_Float16)(a0[1] + bv[ni]);
        half2v p1; p1[0] = (_Float16)(a0[2] + bv[ni]); p1[1] = (_Float16)(a0[3] + bv[ni]);
        uint2 pk;
        pk.x = __builtin_bit_cast(uint32_t, p0);
        pk.y = __builtin_bit_cast(uint32_t, p1);
        *(uint2*)(gxo + ((size_t)tloc*GG + wrow)*4) = pk;
      }
    }
  }
}

// ---------------------------------------------------------------------------
// MFMA recurrence for one (l, 4-batch group, chunk). 704 thr (11 waves).
// m-duplication: only A/D rows 4q matter. Lane (n15, quad): all 4 gates of
// element e = wv*16+n15, batch gb = bg*4+quad.
// ---------------------------------------------------------------------------
__device__ __forceinline__ void rec_body(
    int l, int bg, int ch, const int* lengths,
    const uint32_t* whhw, const uint16_t* gxs, uint32_t* hring,
    float* state_c, uint32_t* state_h, uint32_t* smem, int tid) {

  const int gb0 = bg*4;
  int maxlen = 1;
  #pragma unroll
  for (int bi = 0; bi < 4; ++bi) {
    int L = lengths[gb0 + bi]; if (L < 1) L = 1; if (L > TT) L = TT;
    if (L > maxlen) maxlen = L;
  }
  const int t0 = ch*CC;
  if (t0 >= maxlen) return;                     // group fully frozen
  int t1 = t0 + CC; if (t1 > maxlen) t1 = maxlen;
  const int nst = t1 - t0;

  const int wv = tid >> 6, ln = tid & 63;
  const int quad = ln >> 4, n15 = ln & 15;
  const int e = wv*16 + n15;                    // 0..175
  const int evalid = (e < HH);
  const int gb = gb0 + quad;                    // this lane's batch

  int lenq = lengths[gb]; if (lenq < 1) lenq = 1; if (lenq > TT) lenq = TT;

  // resident W_hh fragments: 4 gates x 6 k-steps, half8 each (96 regs/AGPRs)
  half8 wB[24];
  {
    const half8* wb8 = (const half8*)(whhw + (size_t)l*GP*KPD);
    #pragma unroll
    for (int g = 0; g < 4; ++g) {
      int row = g*EP + e;
      #pragma unroll
      for (int kk = 0; kk < 6; ++kk)
        wB[g*6 + kk] = wb8[(size_t)row*24 + kk*4 + quad];
    }
  }

  float creg = 0.f;
  if (ch > 0 && evalid)
    creg = state_c[((size_t)l*BB + gb)*HH + e];

  // h double buffer in LDS: rows m=0..15, row m = batch gb0+(m>>2)
  uint32_t* hb0 = smem;
  uint32_t* hb1 = smem + 1600;
  for (int i2 = tid; i2 < 1600; i2 += 704) {
    int bb = i2 / 100, dd = i2 - bb*100;
    uint32_t v = 0;
    if (dd < 96 && ch > 0) v = state_h[((size_t)l*BB + gb0 + (bb >> 2))*96 + dd];
    hb0[i2] = v; hb1[i2] = v;
  }
  __syncthreads();

  // per-lane h bits for its (batch gb, element e)
  uint16_t hbit = ((const uint16_t*)hb0)[(quad*4)*200 + e];

  // single incrementing gx pointer; gate offsets are compile-time constants
  const uint16_t* gpt = gxs + (((size_t)(l*16 + bg)*CC)*GG)*4
                            + (size_t)e*4 + quad;
  uint16_t gxv[4];
  #pragma unroll
  for (int g = 0; g < 4; ++g) gxv[g] = gpt[g*(HH*4)];
  gpt += GG*4;

  // direct ring-publish pointer (u16), +192 halves per t
  const int dorb = (l < 2);
  uint16_t* rp;
  {
    uint16_t* hrb16 = (uint16_t*)(hring + ((size_t)(l*2 + (ch & 1))*BB)*CC*96);
    rp = hrb16 + ((size_t)gb*CC)*192 + e;
  }

  const int lo = n15*100 + quad*4;              // af lane offset (dwords)
  const int ho_off = (quad*4)*200 + e;          // hout u16 offset

  int p = 0;
  for (int it = 0; it < nst; ++it) {
    const int t = t0 + it;
    uint32_t* hin  = p ? hb1 : hb0;
    uint32_t* hout = p ? hb0 : hb1;

    // consume current gx (cvt only; added after the MFMA chain)
    float gxf0 = (float)__builtin_bit_cast(_Float16, gxv[0]);
    float gxf1 = (float)__builtin_bit_cast(_Float16, gxv[1]);
    float gxf2 = (float)__builtin_bit_cast(_Float16, gxv[2]);
    float gxf3 = (float)__builtin_bit_cast(_Float16, gxv[3]);
    // prefetch next row (last iter reads in-bounds junk, discarded)
    #pragma unroll
    for (int g = 0; g < 4; ++g) gxv[g] = gpt[g*(HH*4)];
    gpt += GG*4;

    // recurrent projection, C=0 on first MFMA (no splat init)
    f32x4 acc0, acc1, acc2, acc3;
    {
      const f32x4 z = {0.f, 0.f, 0.f, 0.f};
      half8 af = *(const half8*)&hin[lo];
      acc0 = __builtin_amdgcn_mfma_f32_16x16x32_f16(af, wB[0],  z, 0, 0, 0);
      acc1 = __builtin_amdgcn_mfma_f32_16x16x32_f16(af, wB[6],  z, 0, 0, 0);
      acc2 = __builtin_amdgcn_mfma_f32_16x16x32_f16(af, wB[12], z, 0, 0, 0);
      acc3 = __builtin_amdgcn_mfma_f32_16x16x32_f16(af, wB[18], z, 0, 0, 0);
    }
    #pragma unroll
    for (int kk = 1; kk < 6; ++kk) {
      half8 af = *(const half8*)&hin[lo + kk*16];
      acc0 = __builtin_amdgcn_mfma_f32_16x16x32_f16(af, wB[kk],      acc0, 0, 0, 0);
      acc1 = __builtin_amdgcn_mfma_f32_16x16x32_f16(af, wB[6 + kk],  acc1, 0, 0, 0);
      acc2 = __builtin_amdgcn_mfma_f32_16x16x32_f16(af, wB[12 + kk], acc2, 0, 0, 0);
      acc3 = __builtin_amdgcn_mfma_f32_16x16x32_f16(af, wB[18 + kk], acc3, 0, 0, 0);
    }
    // cell update: ONE slot per lane (D row quad*4)
    {
      float gi = acc0[0] + gxf0;
      float gf = acc1[0] + gxf1;
      float gg2 = acc2[0] + gxf2;
      float go = acc3[0] + gxf3;
      float cn = sigmf(gf)*creg + sigmf(gi)*tanhf_(gg2);
      float hv = sigmf(go)*tanhf_(cn);
      if (t < lenq) {                           // per-batch freeze
        creg = cn;
        _Float16 h16 = (_Float16)hv;
        hbit = __builtin_bit_cast(uint16_t, h16);
      }
      if (evalid) {
        ((uint16_t*)hout)[ho_off] = hbit;       // single write (row quad*4)
        if (dorb) *rp = hbit;                   // ring row it = h(t)
      }
      rp += 192;
    }
    // lgkm-only barrier: no vmcnt drain (ring stores / gx prefetch float)
    asm volatile("s_waitcnt lgkmcnt(0)" ::: "memory");
    __builtin_amdgcn_s_barrier();
    p ^= 1;
  }

  // persist state (ring already fully published per-step)
  uint32_t* hfin = p ? hb1 : hb0;
  uint32_t* shb = state_h + ((size_t)l*BB + gb0)*96;
  for (int i2 = tid; i2 < 4*96; i2 += 704) {
    int bb = i2 / 96, dd = i2 - bb*96;
    shb[(size_t)bb*96 + dd] = hfin[(bb*4)*100 + dd];
  }
  if (evalid)
    state_c[((size_t)l*BB + gb)*HH + e] = creg;
}

// ---------------------------------------------------------------------------
// fused step: blocks 0..GEMM_BLKS-1 = gemm(l, bg16, tslice, ch=j-2l),
//             blocks GEMM_BLKS..+47 = rec(l, bg4, ch=j-2l-1)
// ---------------------------------------------------------------------------
__global__ __launch_bounds__(704, 1) void kstep_f(
    int j, const int* lengths, const float* x,
    const uint32_t* wihw, const uint32_t* whhw,
    const float* b0, const float* b1, const float* b2,
    uint16_t* gx, uint32_t* hring, float* state_c, uint32_t* state_h) {
  __shared__ __align__(16) uint32_t smem[TSL*1600];     // 51.2 KB
  const int blk = blockIdx.x, tid = threadIdx.x;
  if (blk < GEMM_BLKS) {
    const int l = blk / (4*NSL);
    const int r = blk - l*(4*NSL);
    const int bg = r / NSL, ts = r - bg*NSL;
    const int ch = j - 2*l;
    if (ch < 0 || ch >= NCH) return;
    const float* bp = (l == 0) ? b0 : ((l == 1) ? b1 : b2);
    uint16_t* gxs = gx + (size_t)(ch & 1)*GX_SLOT_HALVES;
    gemm_body(l, bg, ts, ch, lengths, x, wihw, hring, bp, gxs, smem, tid);
  } else {
    const int idx = blk - GEMM_BLKS;
    if (idx >= REC_BLKS) return;
    const int l = idx >> 4, bg = idx & 15;
    const int ch = j - 2*l - 1;
    if (ch < 0 || ch >= NCH) return;
    const uint16_t* gxs = gx + (size_t)(ch & 1)*GX_SLOT_HALVES;
    rec_body(l, bg, ch, lengths, whhw, gxs, hring,
             state_c, state_h, smem, tid);
  }
}

// ---- sequential fallback (1 gx slot; gemm(i) then rec(i) each iteration) ----
__global__ __launch_bounds__(704, 1) void kgemm_s(
    int step, const int* lengths, const float* x,
    const uint32_t* wihw, const float* b0, const float* b1, const float* b2,
    uint16_t* gx, const uint32_t* hring) {
  __shared__ __align__(16) uint32_t smem[TSL*1600];
  const int blk = blockIdx.x;
  const int l = blk / (4*NSL);
  const int r = blk - l*(4*NSL);
  const int bg = r / NSL, ts = r - bg*NSL;
  const int ch = step - l;
  if (ch < 0 || ch >= NCH) return;
  const float* bp = (l == 0) ? b0 : ((l == 1) ? b1 : b2);
  gemm_body(l, bg, ts, ch, lengths, x, wihw, hring, bp, gx, smem, threadIdx.x);
}

__global__ __launch_bounds__(704, 1) void krec_s(
    int step, const int* lengths,
    const uint32_t* whhw, const uint16_t* gx, uint32_t* hring,
    float* state_c, uint32_t* state_h) {
  __shared__ __align__(16) uint32_t smem[TSL*1600];
  const int idx = blockIdx.x;
  const int l = idx >> 4, bg = idx & 15;
  const int ch = step - l;
  if (ch < 0 || ch >= NCH) return;
  rec_body(l, bg, ch, lengths, whhw, gx, hring,
           state_c, state_h, smem, threadIdx.x);
}

// ---------------------------------------------------------------------------
// FC epilogue on layer-2 final hidden state
// ---------------------------------------------------------------------------
__global__ void kfc(const float* fcw, const float* fcb,
                    const uint32_t* state_h, float* out) {
  int b = blockIdx.x, o = threadIdx.x;
  if (o >= 7) return;
  const uint16_t* h16 = (const uint16_t*)(state_h + (size_t)(2*BB + b)*96);
  float s = fcb[o];
  for (int m = 0; m < HH; ++m) {
    _Float16 hv = __builtin_bit_cast(_Float16, h16[m]);
    s += fcw[o*HH + m] * (float)hv;
  }
  out[b*7 + o] = s;
}

// ---------------------------------------------------------------------------
extern "C" void kernel_launch(void* const* d_in, const int* in_sizes, int n_in,
                              void* d_out, int out_size, void* d_ws, size_t ws_size,
                              hipStream_t stream) {
  const float* x      = (const float*)d_in[0];
  const int*  lengths = (const int*)  d_in[1];
  const float* wih0   = (const float*)d_in[2];
  const float* whh0   = (const float*)d_in[3];
  const float* b0     = (const float*)d_in[4];
  const float* wih1   = (const float*)d_in[5];
  const float* whh1   = (const float*)d_in[6];
  const float* b1     = (const float*)d_in[7];
  const float* wih2   = (const float*)d_in[8];
  const float* whh2   = (const float*)d_in[9];
  const float* b2     = (const float*)d_in[10];
  const float* fcw    = (const float*)d_in[11];
  const float* fcb    = (const float*)d_in[12];

  const size_t off_wih = 0;
  const size_t off_whh = SZ_WIH;
  const size_t off_gx  = SZ_WIH + SZ_WHH;
  const size_t tail    = SZ_HR + SZ_SC + SZ_SH;
  const size_t need_fused = off_gx + 2*SZ_GX1 + tail;
  const size_t need_seq   = off_gx + 1*SZ_GX1 + tail;
  const int fused = (ws_size >= need_fused);
  if (!fused && ws_size < need_seq) return;             // loud, clean failure
  const size_t gx_bytes = fused ? 2*SZ_GX1 : SZ_GX1;
  const size_t off_hr = off_gx + gx_bytes;
  const size_t off_sc = off_hr + SZ_HR;
  const size_t off_sh = off_sc + SZ_SC;

  char* ws = (char*)d_ws;
  _Float16* wih16 = (_Float16*)(ws + off_wih);
  _Float16* whh16 = (_Float16*)(ws + off_whh);
  uint16_t* gxw   = (uint16_t*)(ws + off_gx);
  uint32_t* hrw   = (uint32_t*)(ws + off_hr);
  float*    scw   = (float*)   (ws + off_sc);
  uint32_t* shw   = (uint32_t*)(ws + off_sh);

  hipLaunchKernelGGL(kprep_w, dim3((3*GP*KPH + 255)/256), dim3(256), 0, stream,
                     wih0, whh0, wih1, whh1, wih2, whh2, wih16, whh16);
  hipLaunchKernelGGL(kzero, dim3((HR_DW + 255)/256), dim3(256), 0, stream,
                     hrw, HR_DW);

  if (fused) {
    for (int jj = 0; jj <= NCH + 4; ++jj) {             // j = 0..36
      hipLaunchKernelGGL(kstep_f, dim3(GEMM_BLKS + REC_BLKS), dim3(704), 0,
                         stream, jj, lengths, x, (const uint32_t*)wih16,
                         (const uint32_t*)whh16, b0, b1, b2,
                         gxw, hrw, scw, shw);
    }
  } else {
    for (int i = 0; i < NCH + 2; ++i) {
      hipLaunchKernelGGL(kgemm_s, dim3(GEMM_BLKS), dim3(704), 0, stream,
                         i, lengths, x, (const uint32_t*)wih16,
                         b0, b1, b2, gxw, (const uint32_t*)hrw);
      hipLaunchKernelGGL(krec_s, dim3(REC_BLKS), dim3(704), 0, stream,
                         i, lengths, (const uint32_t*)whh16,
                         (const uint16_t*)gxw, hrw, scw, shw);
    }
  }

  hipLaunchKernelGGL(kfc, dim3(64), dim3(64), 0, stream,
                     fcw, fcb, shw, (float*)d_out);
}